// Round 4
// baseline (345.920 us; speedup 1.0000x reference)
//
#include <hip/hip_runtime.h>
#include <stdint.h>

// Problem constants
#define HW   196   // patches per image
#define CC   384   // embed dim
#define HH   6     // heads
#define DD   64    // head dim
#define MM   25    // support tokens (n*k)
#define PP   75    // query images (n*q)
#define BB   8
#define KVS  70    // kv LDS row stride in ushorts (140 B; dword stride 35 = odd -> conflict-free)
#define NT   512

#define OQ_SIZE (BB * PP * MM * CC)   // 5,760,000 o_query elements

// DTYPE MAP (established R0-R3): inputs fp32 (R1: bf16 read -> NaN proves fp32),
// outputs fp32 (reference returns float32; harness rule "else float*"; R2/R3's
// bit-identical 4.31 absmax = bf16-pair-as-fp32 decode garbage proves it).
__device__ __forceinline__ float bflo(uint32_t u) { return __uint_as_float(u << 16); }
__device__ __forceinline__ float bfhi(uint32_t u) { return __uint_as_float(u & 0xffff0000u); }
__device__ __forceinline__ uint16_t f2bf(float f) {
    uint32_t u = __float_as_uint(f);
    u += 0x7fffu + ((u >> 16) & 1);   // round-to-nearest-even
    return (uint16_t)(u >> 16);
}
__device__ __forceinline__ uint32_t pack2bf(float a, float b) {
    return (uint32_t)f2bf(a) | ((uint32_t)f2bf(b) << 16);
}

__global__ __launch_bounds__(NT) void attn_kernel(
    const float* __restrict__ xq,       // (B, P, HW, C) fp32
    const float* __restrict__ xs,       // (B, M, C) fp32
    float* __restrict__ out,            // o_query (B, P, M, C) fp32
    float* __restrict__ out_sup)        // o_support = copy of x_support, fp32
{
    __shared__ __align__(16) uint16_t kv[HW * KVS];   // 27,440 B (kv tile as bf16, row-major [w][d])
    __shared__ __align__(16) float sc[MM * HW];       // 19,600 B (scores -> softmax probs)
    __shared__ __align__(16) union {
        float qs[MM * DD];                            //  6,400 B (live: load..score phase)
        float part[2 * MM * DD];                      // 12,800 B (live: phase2..phase3)
    } u;                                              // total LDS = 59,840 B (<64 KB, 2 blocks/CU)

    const int bid = blockIdx.x;        // [0, B*P*H)
    const int h   = bid % HH;
    const int bp  = bid / HH;          // [0, B*P)
    const int b   = bp / PP;
    const int tid = threadIdx.x;

    // ---- fold-in: o_support = x_support (fp32 copy). 76,800 floats over blocks 0..599
    if (bid < 600 && tid < 16) {
        int idx = bid * 16 + tid;                    // [0, 9600), 8 floats each
        float4 a = ((const float4*)xs)[idx * 2];
        float4 c = ((const float4*)xs)[idx * 2 + 1];
        ((float4*)out_sup)[idx * 2]     = a;         // out_sup byte offset 23,040,000: 16B-aligned
        ((float4*)out_sup)[idx * 2 + 1] = c;
    }

    // ---- stage kv tile (196 x 64 fp32 -> bf16 in LDS) and qs (25 x 64 fp32)
    {
        const float* src = xq + (size_t)bp * (HW * CC) + h * DD;
        for (int i = tid; i < HW * 16; i += NT) {     // 3136 x float4
            int w = i >> 4, seg = i & 15;
            float4 v = *(const float4*)(src + (size_t)w * CC + seg * 4);
            uint32_t* dst = (uint32_t*)(kv + w * KVS + seg * 4);  // byte 140w+8seg: 4B-aligned stores
            dst[0] = pack2bf(v.x, v.y);
            dst[1] = pack2bf(v.z, v.w);
        }
        const float* sq = xs + (size_t)b * (MM * CC) + h * DD;
        for (int i = tid; i < MM * 16; i += NT) {     // 400 x float4
            int m = i >> 4, seg = i & 15;
            float4 v = *(const float4*)(sq + (size_t)m * CC + seg * 4);
            *(float4*)(u.qs + m * DD + seg * 4) = v;  // byte 256m+16seg: 16B-aligned
        }
    }
    __syncthreads();

    // ---- phase 1: scores. task (mg, w): 5 m's per thread for kv register reuse.
    for (int t = tid; t < 5 * HW; t += NT) {
        int w  = t % HW;
        int mg = t / HW;
        const uint16_t* kvr = kv + w * KVS;
        const float* qb = u.qs + (mg * 5) * DD;
        float a0 = 0.f, a1 = 0.f, a2 = 0.f, a3 = 0.f, a4 = 0.f;
        #pragma unroll 8
        for (int j = 0; j < 32; j++) {                // 2 d's per step
            uint32_t kk = *(const uint32_t*)(kvr + 2 * j);   // byte 140w+4j: 4B-aligned
            float k0 = bflo(kk), k1 = bfhi(kk);
            float2 q0 = *(const float2*)(qb + 0 * DD + 2 * j);  // broadcast reads (same addr in wave)
            float2 q1 = *(const float2*)(qb + 1 * DD + 2 * j);
            float2 q2 = *(const float2*)(qb + 2 * DD + 2 * j);
            float2 q3 = *(const float2*)(qb + 3 * DD + 2 * j);
            float2 q4 = *(const float2*)(qb + 4 * DD + 2 * j);
            a0 += q0.x * k0 + q0.y * k1;
            a1 += q1.x * k0 + q1.y * k1;
            a2 += q2.x * k0 + q2.y * k1;
            a3 += q3.x * k0 + q3.y * k1;
            a4 += q4.x * k0 + q4.y * k1;
        }
        sc[(mg * 5 + 0) * HW + w] = a0 * 0.125f;
        sc[(mg * 5 + 1) * HW + w] = a1 * 0.125f;
        sc[(mg * 5 + 2) * HW + w] = a2 * 0.125f;
        sc[(mg * 5 + 3) * HW + w] = a3 * 0.125f;
        sc[(mg * 5 + 4) * HW + w] = a4 * 0.125f;
    }
    __syncthreads();

    // ---- softmax over w (196) per row m: one wave per row
    {
        int wave = tid >> 6, lane = tid & 63;
        for (int m = wave; m < MM; m += (NT / 64)) {
            float* row = sc + m * HW;
            float v0 = row[lane];
            float v1 = row[lane + 64];
            float v2 = row[lane + 128];
            float v3 = (lane < HW - 192) ? row[lane + 192] : -1e30f;
            float mx = fmaxf(fmaxf(v0, v1), fmaxf(v2, v3));
            #pragma unroll
            for (int off = 32; off > 0; off >>= 1)
                mx = fmaxf(mx, __shfl_xor(mx, off, 64));
            v0 = __expf(v0 - mx);
            v1 = __expf(v1 - mx);
            v2 = __expf(v2 - mx);
            v3 = (lane < HW - 192) ? __expf(v3 - mx) : 0.f;
            float sum = v0 + v1 + v2 + v3;
            #pragma unroll
            for (int off = 32; off > 0; off >>= 1)
                sum += __shfl_xor(sum, off, 64);
            float inv = 1.0f / sum;
            row[lane]       = v0 * inv;
            row[lane + 64]  = v1 * inv;
            row[lane + 128] = v2 * inv;
            if (lane < HW - 192) row[lane + 192] = v3 * inv;
        }
    }
    __syncthreads();

    // ---- phase 2: O = P * kv. task (mg, c, d2): 5 m's x 2 d's, w split into 2 chunks of 98.
    for (int t = tid; t < 320; t += NT) {
        int d2 = t & 31;
        int c  = (t >> 5) & 1;
        int mg = t >> 6;
        int w0 = c * 98;
        const float* pr = sc + (mg * 5) * HW;
        float x0 = 0.f, y0 = 0.f, x1 = 0.f, y1 = 0.f, x2 = 0.f, y2 = 0.f,
              x3 = 0.f, y3 = 0.f, x4 = 0.f, y4 = 0.f;
        #pragma unroll 2
        for (int w = w0; w < w0 + 98; w++) {
            uint32_t kk = *(const uint32_t*)(kv + w * KVS + 2 * d2);  // 4B-aligned
            float k0 = bflo(kk), k1 = bfhi(kk);
            float p0 = pr[0 * HW + w], p1 = pr[1 * HW + w], p2 = pr[2 * HW + w],
                  p3 = pr[3 * HW + w], p4 = pr[4 * HW + w];
            x0 += p0 * k0; y0 += p0 * k1;
            x1 += p1 * k0; y1 += p1 * k1;
            x2 += p2 * k0; y2 += p2 * k1;
            x3 += p3 * k0; y3 += p3 * k1;
            x4 += p4 * k0; y4 += p4 * k1;
        }
        float* dst = u.part + (c * MM + mg * 5) * DD + 2 * d2;
        dst[0 * DD + 0] = x0; dst[0 * DD + 1] = y0;
        dst[1 * DD + 0] = x1; dst[1 * DD + 1] = y1;
        dst[2 * DD + 0] = x2; dst[2 * DD + 1] = y2;
        dst[3 * DD + 0] = x3; dst[3 * DD + 1] = y3;
        dst[4 * DD + 0] = x4; dst[4 * DD + 1] = y4;
    }
    __syncthreads();

    // ---- phase 3: reduce 2 partials, coalesced fp32 float4 stores
    float* ob = out + (size_t)bp * (MM * CC) + h * DD;
    for (int t = tid; t < MM * 16; t += NT) {
        int m = t >> 4, d4 = t & 15;
        float4 a  = *(const float4*)(u.part + m * DD + d4 * 4);
        float4 b4 = *(const float4*)(u.part + (MM + m) * DD + d4 * 4);
        float4 o;
        o.x = a.x + b4.x;
        o.y = a.y + b4.y;
        o.z = a.z + b4.z;
        o.w = a.w + b4.w;
        *(float4*)(ob + (size_t)m * CC + d4 * 4) = o;   // byte 4*(768m+128h... wait) -> 16B-aligned
    }
}

extern "C" void kernel_launch(void* const* d_in, const int* in_sizes, int n_in,
                              void* d_out, int out_size, void* d_ws, size_t ws_size,
                              hipStream_t stream) {
    const float* xq = (const float*)d_in[0];   // x_query  fp32, 45,158,400 elems
    const float* xs = (const float*)d_in[1];   // x_support fp32, 76,800 elems
    float* out = (float*)d_out;
    float* out_sup = out + (size_t)OQ_SIZE;
    attn_kernel<<<BB * PP * HH, NT, 0, stream>>>(xq, xs, out, out_sup);
}

// Round 5
// 275.756 us; speedup vs baseline: 1.2544x; 1.2544x over previous
//
#include <hip/hip_runtime.h>
#include <stdint.h>

// Problem constants
#define HW   196   // patches per image
#define CC   384   // embed dim
#define HH   6     // heads
#define DD   64    // head dim
#define MM   25    // support tokens (n*k)
#define PP   75    // query images (n*q)
#define BB   8
#define NT   512

#define KVW  35    // kv row stride in dwords (70 bf16); 35 mod 32 = 3 (odd) -> <=2-way banks
#define KTW  115   // kvT row stride in dwords (230 bf16); 115 mod 32 = 19 -> <=2-way
#define SCW  113   // scb row stride in dwords (226 bf16); 113 mod 32 = 17 -> <=2-way

#define OQ_SIZE (BB * PP * MM * CC)   // 5,760,000 o_query elements

// DTYPE MAP (established R0-R4): inputs fp32, outputs fp32.
typedef float  f32x4 __attribute__((ext_vector_type(4)));
typedef short  s16x8 __attribute__((ext_vector_type(8)));
union Frag { uint32_t u[4]; s16x8 v; };

__device__ __forceinline__ float bflo(uint32_t u) { return __uint_as_float(u << 16); }
__device__ __forceinline__ float bfhi(uint32_t u) { return __uint_as_float(u & 0xffff0000u); }
__device__ __forceinline__ uint16_t f2bf(float f) {
    uint32_t u = __float_as_uint(f);
    u += 0x7fffu + ((u >> 16) & 1);   // RNE
    return (uint16_t)(u >> 16);
}
__device__ __forceinline__ uint32_t pack2bf(float a, float b) {
    return (uint32_t)f2bf(a) | ((uint32_t)f2bf(b) << 16);
}

__global__ __launch_bounds__(NT) void attn_kernel(
    const float* __restrict__ xq,       // (B, P, HW, C) fp32
    const float* __restrict__ xs,       // (B, M, C) fp32
    float* __restrict__ out,            // o_query (B, P, M, C) fp32
    float* __restrict__ out_sup)        // o_support = copy of x_support fp32
{
    // kv (row-major [w][d], bf16) lives staging..phase1; kvT ([d][w], bf16) lives
    // transpose-write..phase2 -> union. scb: bf16 scores -> softmax probs.
    __shared__ union {
        uint32_t kv[208 * KVW];    // 29,120 B (rows 196..207 zeroed)
        uint32_t kvT[64 * KTW];    // 29,440 B
    } U;                                           // 29,440 B
    __shared__ uint32_t scb[32 * SCW];             // 14,464 B  (total 43,904 -> 3 blocks/CU)

    const int bid  = blockIdx.x;       // [0, B*P*H)
    const int h    = bid % HH;
    const int bp   = bid / HH;         // [0, B*P)
    const int b    = bp / PP;
    const int tid  = threadIdx.x;
    const int lane = tid & 63;
    const int wv   = tid >> 6;
    const int lm   = lane & 15;        // MFMA n/m index
    const int quad = lane >> 4;        // MFMA quad

    // ---- fold-in: o_support = x_support (fp32 copy)
    if (bid < 600 && tid < 16) {
        int idx = bid * 16 + tid;
        ((float4*)out_sup)[idx * 2]     = ((const float4*)xs)[idx * 2];
        ((float4*)out_sup)[idx * 2 + 1] = ((const float4*)xs)[idx * 2 + 1];
    }

    // ---- phase1 A-frags (qs * SCALE -> bf16) straight from global (L2-hot, wave-uniform slab)
    // A layout [m89/m118]: lane holds A[m = lm][k = quad*8 + j]
    Frag afr[2][2];                    // [m-tile][k-step]
    #pragma unroll
    for (int mt = 0; mt < 2; mt++) {
        int row = 16 * mt + lm;
        #pragma unroll
        for (int ks = 0; ks < 2; ks++) {
            if (row < MM) {
                const float* p = xs + (size_t)b * (MM * CC) + row * CC + h * DD + ks * 32 + quad * 8;
                float4 v0 = *(const float4*)p;
                float4 v1 = *(const float4*)(p + 4);
                afr[mt][ks].u[0] = pack2bf(v0.x * 0.125f, v0.y * 0.125f);
                afr[mt][ks].u[1] = pack2bf(v0.z * 0.125f, v0.w * 0.125f);
                afr[mt][ks].u[2] = pack2bf(v1.x * 0.125f, v1.y * 0.125f);
                afr[mt][ks].u[3] = pack2bf(v1.z * 0.125f, v1.w * 0.125f);
            } else {
                afr[mt][ks].u[0] = afr[mt][ks].u[1] = afr[mt][ks].u[2] = afr[mt][ks].u[3] = 0;
            }
        }
    }

    // ---- stage kv (196x64 fp32 -> bf16 LDS row-major) + zero pad rows 196..207
    {
        const float* src = xq + (size_t)bp * (HW * CC) + h * DD;
        for (int i = tid; i < HW * 16; i += NT) {     // 3136 float4
            int w = i >> 4, seg = i & 15;
            float4 v = *(const float4*)(src + (size_t)w * CC + seg * 4);
            U.kv[w * KVW + seg * 2]     = pack2bf(v.x, v.y);
            U.kv[w * KVW + seg * 2 + 1] = pack2bf(v.z, v.w);
        }
        for (int i = tid; i < 12 * 32; i += NT) {     // rows 196..207, data dwords 0..31
            U.kv[(196 + (i >> 5)) * KVW + (i & 31)] = 0;
        }
    }
    __syncthreads();  // B1: kv staged

    // ---- transpose-read: thread holds w-pair {2p,2p+1} x 16 d's (coalesced row reads, ~2-way)
    uint32_t tr[16];
    const int tp  = tid >> 2;          // w-pair [0,104)
    const int tdc = tid & 3;           // d-chunk [0,4): d in [16*tdc, 16*tdc+16)
    if (tid < 416) {
        #pragma unroll
        for (int c = 0; c < 16; c++) {
            int r = c >> 3, cc = c & 7;
            tr[c] = U.kv[(2 * tp + r) * KVW + tdc * 8 + cc];
        }
    }

    // ---- phase1: S = qs . kv^T via MFMA. B layout: lane holds B[k=quad*8+j][n=lm]
    //      = kv[w = 16*nt + lm][d = 32*ks + quad*8 + j]  -> 4 b32 from kv row (odd stride, ~2-way)
    {
        uint16_t* scbh = (uint16_t*)scb;
        for (int nt = wv; nt < 13; nt += 8) {
            f32x4 acc0 = {0.f, 0.f, 0.f, 0.f};
            f32x4 acc1 = {0.f, 0.f, 0.f, 0.f};
            #pragma unroll
            for (int ks = 0; ks < 2; ks++) {
                Frag bf;
                int base = (16 * nt + lm) * KVW + ks * 16 + quad * 4;
                bf.u[0] = U.kv[base + 0];
                bf.u[1] = U.kv[base + 1];
                bf.u[2] = U.kv[base + 2];
                bf.u[3] = U.kv[base + 3];
                acc0 = __builtin_amdgcn_mfma_f32_16x16x32_bf16(afr[0][ks].v, bf.v, acc0, 0, 0, 0);
                acc1 = __builtin_amdgcn_mfma_f32_16x16x32_bf16(afr[1][ks].v, bf.v, acc1, 0, 0, 0);
            }
            int wcol = 16 * nt + lm;   // D: row = m = quad*4+i (+16 for tile1), col = w
            #pragma unroll
            for (int i = 0; i < 4; i++) {
                scbh[(quad * 4 + i) * (2 * SCW) + wcol]        = f2bf(acc0[i]);
                scbh[(16 + quad * 4 + i) * (2 * SCW) + wcol]   = f2bf(acc1[i]);
            }
        }
    }
    __syncthreads();  // B2: scores complete

    // ---- softmax over w per row m (bf16-packed rows; 196 cols = 98 dwords)
    for (int m = wv; m < MM; m += 8) {
        uint32_t* row = scb + m * SCW;
        uint32_t u0 = row[lane];
        uint32_t u1 = (lane < 34) ? row[64 + lane] : 0;
        float f0 = bflo(u0), f1 = bfhi(u0);
        float f2 = (lane < 34) ? bflo(u1) : -1e30f;
        float f3 = (lane < 34) ? bfhi(u1) : -1e30f;
        float mx = fmaxf(fmaxf(f0, f1), fmaxf(f2, f3));
        #pragma unroll
        for (int off = 32; off > 0; off >>= 1) mx = fmaxf(mx, __shfl_xor(mx, off, 64));
        float e0 = __expf(f0 - mx), e1 = __expf(f1 - mx);
        float e2 = (lane < 34) ? __expf(f2 - mx) : 0.f;
        float e3 = (lane < 34) ? __expf(f3 - mx) : 0.f;
        float s = e0 + e1 + e2 + e3;
        #pragma unroll
        for (int off = 32; off > 0; off >>= 1) s += __shfl_xor(s, off, 64);
        float inv = 1.0f / s;
        row[lane] = pack2bf(e0 * inv, e1 * inv);
        if (lane < 34)      row[64 + lane] = pack2bf(e2 * inv, e3 * inv);
        else if (lane < 48) row[64 + lane] = 0;   // zero cols 196..223 (phase2 K-pad)
    }
    __syncthreads();  // B3: all kv reads done -> safe to overwrite with kvT; probs final

    // ---- transpose-write: kvT[d][w] (b32 packs the w-pair; ~2-way banks)
    if (tid < 416) {
        #pragma unroll
        for (int c = 0; c < 16; c++) {
            int d = 16 * tdc + c;
            uint32_t e0 = (tr[c >> 1]     >> (16 * (c & 1))) & 0xffffu;
            uint32_t e1 = (tr[8 + (c >> 1)] >> (16 * (c & 1))) & 0xffffu;
            U.kvT[d * KTW + tp] = e0 | (e1 << 16);
        }
    } else {
        // zero kvT cols 208..223 (dwords 104..111) for all 64 d
        for (int i = tid - 416; i < 64 * 8; i += 96)
            U.kvT[(i >> 3) * KTW + 104 + (i & 7)] = 0;
    }
    __syncthreads();  // B4: kvT ready

    // ---- phase2: O = P . kv via MFMA. Wave -> (m-tile, n-tile); K = 224 (7 steps)
    {
        const int mt  = wv >> 2;
        const int nt2 = wv & 3;
        f32x4 acc = {0.f, 0.f, 0.f, 0.f};
        #pragma unroll
        for (int ks = 0; ks < 7; ks++) {
            Frag a, bf;
            int abase = (16 * mt + lm) * SCW + ks * 16 + quad * 4;   // A = P (bf16 packed)
            a.u[0] = scb[abase + 0];
            a.u[1] = scb[abase + 1];
            a.u[2] = scb[abase + 2];
            a.u[3] = scb[abase + 3];
            int bbase = (16 * nt2 + lm) * KTW + ks * 16 + quad * 4;  // B = kvT row (w-contig)
            bf.u[0] = U.kvT[bbase + 0];
            bf.u[1] = U.kvT[bbase + 1];
            bf.u[2] = U.kvT[bbase + 2];
            bf.u[3] = U.kvT[bbase + 3];
            acc = __builtin_amdgcn_mfma_f32_16x16x32_bf16(a.v, bf.v, acc, 0, 0, 0);
        }
        // D: row = m = 16*mt + quad*4 + i, col = d = 16*nt2 + lm
        float* ob = out + (size_t)bp * (MM * CC) + h * DD + 16 * nt2 + lm;
        #pragma unroll
        for (int i = 0; i < 4; i++) {
            int m = 16 * mt + quad * 4 + i;
            if (m < MM) ob[(size_t)m * CC] = acc[i];
        }
    }
}

extern "C" void kernel_launch(void* const* d_in, const int* in_sizes, int n_in,
                              void* d_out, int out_size, void* d_ws, size_t ws_size,
                              hipStream_t stream) {
    const float* xq = (const float*)d_in[0];   // x_query  fp32
    const float* xs = (const float*)d_in[1];   // x_support fp32
    float* out = (float*)d_out;
    float* out_sup = out + (size_t)OQ_SIZE;
    attn_kernel<<<BB * PP * HH, NT, 0, stream>>>(xq, xs, out, out_sup);
}